// Round 2
// baseline (345.153 us; speedup 1.0000x reference)
//
#include <hip/hip_runtime.h>
#include <hip/hip_bf16.h>
#include <math.h>

typedef unsigned short u16;
typedef __bf16 v8bf __attribute__((ext_vector_type(8)));
typedef float f32x4 __attribute__((ext_vector_type(4)));

// ---------- bf16 helpers (raw ushort representation) ----------
__device__ __forceinline__ float us2f(u16 h) {
    union { unsigned int u; float f; } v; v.u = ((unsigned int)h) << 16; return v.f;
}
__device__ __forceinline__ u16 f2us(float f) {
    union { float f; unsigned int u; } v; v.f = f;
    unsigned int r = v.u + 0x7fffu + ((v.u >> 16) & 1u);   // RNE
    return (u16)(r >> 16);
}
__device__ __forceinline__ float gelu_f(float x) {
    return 0.5f * x * (1.0f + erff(x * 0.70710678118654752f));
}
// global -> LDS direct load, 16B per lane
__device__ __forceinline__ void gload_lds16(const u16* g, u16* l) {
    auto gp = reinterpret_cast<const __attribute__((address_space(1))) unsigned int*>(
        (uintptr_t)g);
    auto lp = reinterpret_cast<__attribute__((address_space(3))) unsigned int*>(
        (uintptr_t)l);
    __builtin_amdgcn_global_load_lds(gp, lp, 16, 0, 0);
}

// ---------- f32 -> bf16 convert (n multiple of 8) ----------
__global__ __launch_bounds__(256) void cvt_kernel(const float* __restrict__ in,
                                                  u16* __restrict__ out, int n)
{
    const int i = (blockIdx.x * 256 + threadIdx.x) * 8;
    if (i >= n) return;
    float4 a = *reinterpret_cast<const float4*>(in + i);
    float4 b = *reinterpret_cast<const float4*>(in + i + 4);
    u16 o[8] = { f2us(a.x), f2us(a.y), f2us(a.z), f2us(a.w),
                 f2us(b.x), f2us(b.y), f2us(b.z), f2us(b.w) };
    *reinterpret_cast<uint4*>(out + i) = *reinterpret_cast<uint4*>(o);
}

// ---------- LayerNorm: one block per row, D=1024, 256 threads; bf16 out ----------
template<typename TIN>
__global__ __launch_bounds__(256) void ln_kernel(const TIN* __restrict__ in,
                                                 const float* __restrict__ g,
                                                 const float* __restrict__ b,
                                                 u16* __restrict__ out)
{
    const int row = blockIdx.x, tid = threadIdx.x;
    const size_t base = (size_t)row * 1024 + tid * 4;
    float x0, x1, x2, x3;
    if constexpr (sizeof(TIN) == 4) {
        float4 v = *reinterpret_cast<const float4*>(in + base);
        x0 = v.x; x1 = v.y; x2 = v.z; x3 = v.w;
    } else {
        ushort4 v = *reinterpret_cast<const ushort4*>((const u16*)in + base);
        x0 = us2f(v.x); x1 = us2f(v.y); x2 = us2f(v.z); x3 = us2f(v.w);
    }
    float s = x0 + x1 + x2 + x3;
    float q = x0*x0 + x1*x1 + x2*x2 + x3*x3;
    #pragma unroll
    for (int o = 32; o; o >>= 1) { s += __shfl_down(s, o); q += __shfl_down(q, o); }
    __shared__ float red[8];
    if ((tid & 63) == 0) { red[tid >> 6] = s; red[4 + (tid >> 6)] = q; }
    __syncthreads();
    s = red[0] + red[1] + red[2] + red[3];
    q = red[4] + red[5] + red[6] + red[7];
    const float mu = s * (1.0f / 1024.0f);
    const float rs = rsqrtf(q * (1.0f / 1024.0f) - mu * mu + 1e-5f);
    float4 gv = *reinterpret_cast<const float4*>(g + tid * 4);
    float4 bv = *reinterpret_cast<const float4*>(b + tid * 4);
    ushort4 o4;
    o4.x = f2us((x0 - mu) * rs * gv.x + bv.x);
    o4.y = f2us((x1 - mu) * rs * gv.y + bv.y);
    o4.z = f2us((x2 - mu) * rs * gv.z + bv.z);
    o4.w = f2us((x3 - mu) * rs * gv.w + bv.w);
    *reinterpret_cast<ushort4*>(out + base) = o4;
}

// ---------- prep: B_bar concat (128x1024) and C2 concat (1024x128), bf16 ----------
__global__ __launch_bounds__(256) void prep_kernel(
    const float* __restrict__ Lre, const float* __restrict__ Lim, const float* __restrict__ lstep,
    const float* __restrict__ Bre, const float* __restrict__ Bim,
    const float* __restrict__ Cre, const float* __restrict__ Cim,
    u16* __restrict__ Bbar, u16* __restrict__ C2)
{
    const int idx = blockIdx.x * 256 + threadIdx.x;   // 0..131071
    if (idx < 65536) {
        const int p = idx >> 10, d = idx & 1023;
        const float lr = Lre[p], li = Lim[p];
        const float dt = expf(lstep[p]);
        const float er = expf(lr * dt);
        const float ar = er * cosf(li * dt), ai = er * sinf(li * dt); // Lam_bar
        const float nr = ar - 1.0f, ni = ai;
        const float den = lr * lr + li * li;
        const float cr = (nr * lr + ni * li) / den;   // coef = (Lam_bar-1)/Lam
        const float ci = (ni * lr - nr * li) / den;
        const float br = Bre[idx], bi = Bim[idx];
        Bbar[p * 1024 + d]        = f2us(cr * br - ci * bi);   // Re row p
        Bbar[(64 + p) * 1024 + d] = f2us(cr * bi + ci * br);   // Im row 64+p
    } else {
        const int i = idx - 65536;          // over (d,p): i = d*64+p
        const int d = i >> 6, p = i & 63;
        C2[d * 128 + p]      = f2us( 2.0f * Cre[i]);
        C2[d * 128 + 64 + p] = f2us(-2.0f * Cim[i]);
    }
}

// ---------- scan: one block per (b,p); chunked scan, chunk=8, 256 threads ----------
__global__ __launch_bounds__(256) void scan_kernel(
    const float* __restrict__ Bu,    // (8192,128) f32: [:,p]=re, [:,64+p]=im
    const float* __restrict__ Lre, const float* __restrict__ Lim, const float* __restrict__ lstep,
    u16* __restrict__ A2)            // (8192,128) bf16: [:,p]=Xre, [:,64+p]=Xim
{
    const int b = blockIdx.x >> 6;
    const int p = blockIdx.x & 63;
    const int t = threadIdx.x;
    const float lr = Lre[p], li = Lim[p];
    const float dt = expf(lstep[p]);
    const float er = expf(lr * dt);
    const float ar = er * cosf(li * dt), ai = er * sinf(li * dt);  // a = Lam_bar

    const size_t base = ((size_t)b * 2048 + t * 8) * 128;
    float xr[8], xi[8];
    float sr = 0.f, si = 0.f;
    #pragma unroll
    for (int i = 0; i < 8; ++i) {
        const float br = Bu[base + i * 128 + p];
        const float bi = Bu[base + i * 128 + 64 + p];
        const float nr = ar * sr - ai * si + br;
        const float ni = ar * si + ai * sr + bi;
        sr = nr; si = ni;
        xr[i] = sr; xi[i] = si;
    }
    // a^8
    float fr = ar, fi = ai;
    #pragma unroll
    for (int s = 0; s < 3; ++s) { const float t2 = fr*fr - fi*fi; fi = 2.f*fr*fi; fr = t2; }
    // Hillis-Steele over 256 chunk end-states
    __shared__ float Er[256], Ei[256];
    Er[t] = sr; Ei[t] = si;
    __syncthreads();
    float vr = sr, vi = si;
    for (int off = 1; off < 256; off <<= 1) {
        float pr = 0.f, pi = 0.f;
        if (t >= off) { pr = Er[t - off]; pi = Ei[t - off]; }
        __syncthreads();
        vr += fr * pr - fi * pi;
        vi += fr * pi + fi * pr;
        Er[t] = vr; Ei[t] = vi;
        const float nf = fr*fr - fi*fi; fi = 2.f*fr*fi; fr = nf;
        __syncthreads();
    }
    float cr = 0.f, ci = 0.f;
    if (t > 0) { cr = Er[t - 1]; ci = Ei[t - 1]; }
    // x_i += a^{i+1} * carry
    float gr = ar * cr - ai * ci, gi = ar * ci + ai * cr;
    #pragma unroll
    for (int i = 0; i < 8; ++i) {
        xr[i] += gr; xi[i] += gi;
        const float n2 = ar * gr - ai * gi; gi = ar * gi + ai * gr; gr = n2;
    }
    #pragma unroll
    for (int i = 0; i < 8; ++i) {
        const size_t m = (size_t)b * 2048 + t * 8 + i;
        A2[m * 128 + p]      = f2us(xr[i]);
        A2[m * 128 + 64 + p] = f2us(xi[i]);
    }
}

// ---------- MFMA GEMM: C = A(MxK) @ B(NxK)^T, bf16 in, EPI-specific out ----------
// EPI 0: f32 out (Bu). EPI 1: h = gelu(acc + dskip*fx) + fx (bf16 out).
// EPI 2: GEGLU dual-B, e2 = a*gelu(gate) (bf16 out). EPI 3: f32 out = acc + aux.
template<int BM, int BN, int WM, int WN, int EPI>
__global__ __launch_bounds__(WM * WN * 64) void gemm_kernel(
    const u16* __restrict__ A, const u16* __restrict__ B, void* __restrict__ Cout,
    const int M, const int N, const int K,
    const u16* __restrict__ aux, const float* __restrict__ dskip)
{
    constexpr int THREADS = WM * WN * 64;
    constexpr bool GLU = (EPI == 2);
    constexpr int AJ = (BM * 4) / THREADS;   // 16B slots per thread for A tile
    constexpr int BJ = (BN * 4) / THREADS;
    __shared__ u16 lsA[BM * 32];
    __shared__ u16 lsB[BN * 32];
    __shared__ u16 lsB2[GLU ? BN * 32 : 8];
    (void)M;

    const int tid = threadIdx.x;
    const int lane = tid & 63;
    const int wid = tid >> 6;
    const int wm = wid / WN, wn = wid % WN;
    const int m0 = blockIdx.y * BM, n0 = blockIdx.x * BN;

    f32x4 acc[GLU ? 2 : 1][4][4] = {};

    for (int k0 = 0; k0 < K; k0 += 32) {
        #pragma unroll
        for (int j = 0; j < AJ; ++j) {
            const int s = j * THREADS + tid;
            gload_lds16(A + (size_t)(m0 + (s >> 2)) * K + k0 + (s & 3) * 8,
                        lsA + (s - lane) * 8);
        }
        #pragma unroll
        for (int j = 0; j < BJ; ++j) {
            const int s = j * THREADS + tid;
            gload_lds16(B + (size_t)(n0 + (s >> 2)) * K + k0 + (s & 3) * 8,
                        lsB + (s - lane) * 8);
            if constexpr (GLU)
                gload_lds16(B + (size_t)(N + n0 + (s >> 2)) * K + k0 + (s & 3) * 8,
                            lsB2 + (s - lane) * 8);
        }
        __syncthreads();

        v8bf af[4], bfv[4];
        #pragma unroll
        for (int f = 0; f < 4; ++f)
            af[f] = *reinterpret_cast<const v8bf*>(
                lsA + (wm * 64 + f * 16 + (lane & 15)) * 32 + (lane >> 4) * 8);
        #pragma unroll
        for (int f = 0; f < 4; ++f)
            bfv[f] = *reinterpret_cast<const v8bf*>(
                lsB + (wn * 64 + f * 16 + (lane & 15)) * 32 + (lane >> 4) * 8);
        #pragma unroll
        for (int fm = 0; fm < 4; ++fm)
            #pragma unroll
            for (int fn = 0; fn < 4; ++fn)
                acc[0][fm][fn] = __builtin_amdgcn_mfma_f32_16x16x32_bf16(
                    af[fm], bfv[fn], acc[0][fm][fn], 0, 0, 0);
        if constexpr (GLU) {
            #pragma unroll
            for (int f = 0; f < 4; ++f)
                bfv[f] = *reinterpret_cast<const v8bf*>(
                    lsB2 + (wn * 64 + f * 16 + (lane & 15)) * 32 + (lane >> 4) * 8);
            #pragma unroll
            for (int fm = 0; fm < 4; ++fm)
                #pragma unroll
                for (int fn = 0; fn < 4; ++fn)
                    acc[1][fm][fn] = __builtin_amdgcn_mfma_f32_16x16x32_bf16(
                        af[fm], bfv[fn], acc[1][fm][fn], 0, 0, 0);
        }
        __syncthreads();
    }

    #pragma unroll
    for (int fm = 0; fm < 4; ++fm)
    #pragma unroll
    for (int fn = 0; fn < 4; ++fn)
    #pragma unroll
    for (int i = 0; i < 4; ++i) {
        const int r = m0 + wm * 64 + fm * 16 + (lane >> 4) * 4 + i;
        const int c = n0 + wn * 64 + fn * 16 + (lane & 15);
        const size_t o = (size_t)r * N + c;
        const float v = acc[0][fm][fn][i];
        if constexpr (EPI == 0) {
            ((float*)Cout)[o] = v;
        } else if constexpr (EPI == 1) {
            const float u = us2f(aux[o]);
            const float t = v + dskip[c] * u;
            ((u16*)Cout)[o] = f2us(gelu_f(t) + u);
        } else if constexpr (EPI == 2) {
            ((u16*)Cout)[o] = f2us(v * gelu_f(acc[1][fm][fn][i]));
        } else {
            ((float*)Cout)[o] = v + us2f(aux[o]);
        }
    }
}

// ---------- workspace layout (bytes) ----------
// timeline: LN1->fx | cvt->WeB,WdB | prep | G1->Bu | scan->A2 | G2->h(in d_out)
//           | LN2->fx2 | G3->e2 | G4->d_out(f32, overwrites h)
// e2 (33.55MB @ 0) aliases fx+Bu+A2 (+slack), all dead by G3.
static constexpr size_t OFF_FX  = 0;                              // bf16 16.78MB
static constexpr size_t OFF_BU  = 16777216;                       // f32   4.19MB
static constexpr size_t OFF_A2  = 20971520;                       // bf16  2.10MB
static constexpr size_t OFF_E2  = 0;                              // bf16 33.55MB (alias)
static constexpr size_t OFF_FX2 = 33554432;                       // bf16 16.78MB
static constexpr size_t OFF_BB  = 50331648;                       // bf16  0.26MB
static constexpr size_t OFF_C2  = 50593792;                       // bf16  0.26MB
static constexpr size_t OFF_WE  = 50855936;                       // bf16  8.39MB
static constexpr size_t OFF_WD  = 59244544;                       // bf16  4.19MB  (end 63.44MB)

extern "C" void kernel_launch(void* const* d_in, const int* in_sizes, int n_in,
                              void* d_out, int out_size, void* d_ws, size_t ws_size,
                              hipStream_t stream) {
    const float* x    = (const float*)d_in[0];
    const float* l1g  = (const float*)d_in[1];
    const float* l1b  = (const float*)d_in[2];
    const float* l2g  = (const float*)d_in[3];
    const float* l2b  = (const float*)d_in[4];
    const float* Lre  = (const float*)d_in[5];
    const float* Lim  = (const float*)d_in[6];
    const float* Bre  = (const float*)d_in[7];
    const float* Bim  = (const float*)d_in[8];
    const float* Cre  = (const float*)d_in[9];
    const float* Cim  = (const float*)d_in[10];
    const float* Dsk  = (const float*)d_in[11];
    const float* lst  = (const float*)d_in[12];
    const float* Wenc = (const float*)d_in[13];
    const float* Wdec = (const float*)d_in[14];
    float* out = (float*)d_out;

    char* ws = (char*)d_ws;
    u16*   fx   = (u16*)(ws + OFF_FX);
    float* Bu   = (float*)(ws + OFF_BU);
    u16*   A2   = (u16*)(ws + OFF_A2);
    u16*   e2   = (u16*)(ws + OFF_E2);
    u16*   fx2  = (u16*)(ws + OFF_FX2);
    u16*   Bbar = (u16*)(ws + OFF_BB);
    u16*   C2   = (u16*)(ws + OFF_C2);
    u16*   WeB  = (u16*)(ws + OFF_WE);
    u16*   WdB  = (u16*)(ws + OFF_WD);
    u16*   h    = (u16*)d_out;           // h (bf16) lives in d_out's first half

    // 1) fx = LN1(x)  [bf16]
    ln_kernel<float><<<8192, 256, 0, stream>>>(x, l1g, l1b, fx);
    // 1b) weight conversions + B_bar / C2 precompute
    cvt_kernel<<<2048, 256, 0, stream>>>(Wenc, WeB, 4096 * 1024);
    cvt_kernel<<<1024, 256, 0, stream>>>(Wdec, WdB, 1024 * 2048);
    prep_kernel<<<512, 256, 0, stream>>>(Lre, Lim, lst, Bre, Bim, Cre, Cim, Bbar, C2);
    // 2) Bu = fx @ Bbar^T   (8192 x 128, f32)
    gemm_kernel<64, 64, 1, 1, 0><<<dim3(2, 128), 64, 0, stream>>>(
        fx, Bbar, Bu, 8192, 128, 1024, nullptr, nullptr);
    // 3) xs scan -> A2 (bf16)
    scan_kernel<<<256, 256, 0, stream>>>(Bu, Lre, Lim, lst, A2);
    // 4) h = gelu(A2 @ C2^T + Dskip*fx) + fx  [bf16, into d_out]
    gemm_kernel<128, 128, 2, 2, 1><<<dim3(8, 64), 256, 0, stream>>>(
        A2, C2, h, 8192, 1024, 128, fx, Dsk);
    // 5) fx2 = LN2(h)  [bf16]
    ln_kernel<u16><<<8192, 256, 0, stream>>>(h, l2g, l2b, fx2);
    // 6) e2 = (fx2 @ We[:2048]^T) * gelu(fx2 @ We[2048:]^T)  [bf16]
    gemm_kernel<128, 128, 2, 2, 2><<<dim3(16, 64), 256, 0, stream>>>(
        fx2, WeB, e2, 8192, 2048, 1024, nullptr, nullptr);
    // 7) out = e2 @ WdB^T + fx2  [f32]
    gemm_kernel<128, 128, 2, 2, 3><<<dim3(8, 64), 256, 0, stream>>>(
        e2, WdB, out, 8192, 1024, 2048, fx2, nullptr);

    (void)in_sizes; (void)n_in; (void)out_size; (void)ws_size;
}

// Round 3
// 269.473 us; speedup vs baseline: 1.2808x; 1.2808x over previous
//
#include <hip/hip_runtime.h>
#include <hip/hip_bf16.h>
#include <math.h>

typedef unsigned short u16;
typedef __bf16 v8bf __attribute__((ext_vector_type(8)));
typedef float f32x4 __attribute__((ext_vector_type(4)));

// ---------- bf16 helpers (raw ushort representation) ----------
__device__ __forceinline__ float us2f(u16 h) {
    union { unsigned int u; float f; } v; v.u = ((unsigned int)h) << 16; return v.f;
}
__device__ __forceinline__ u16 f2us(float f) {
    union { float f; unsigned int u; } v; v.f = f;
    unsigned int r = v.u + 0x7fffu + ((v.u >> 16) & 1u);   // RNE
    return (u16)(r >> 16);
}
__device__ __forceinline__ float gelu_f(float x) {
    return 0.5f * x * (1.0f + erff(x * 0.70710678118654752f));
}
// global -> LDS direct load, 16B per lane
__device__ __forceinline__ void gload_lds16(const u16* g, u16* l) {
    auto gp = reinterpret_cast<const __attribute__((address_space(1))) unsigned int*>(
        (uintptr_t)g);
    auto lp = reinterpret_cast<__attribute__((address_space(3))) unsigned int*>(
        (uintptr_t)l);
    __builtin_amdgcn_global_load_lds(gp, lp, 16, 0, 0);
}

// ---------- f32 -> bf16 convert (n multiple of 8) ----------
__global__ __launch_bounds__(256) void cvt_kernel(const float* __restrict__ in,
                                                  u16* __restrict__ out, int n)
{
    const int i = (blockIdx.x * 256 + threadIdx.x) * 8;
    if (i >= n) return;
    float4 a = *reinterpret_cast<const float4*>(in + i);
    float4 b = *reinterpret_cast<const float4*>(in + i + 4);
    u16 o[8] = { f2us(a.x), f2us(a.y), f2us(a.z), f2us(a.w),
                 f2us(b.x), f2us(b.y), f2us(b.z), f2us(b.w) };
    *reinterpret_cast<uint4*>(out + i) = *reinterpret_cast<uint4*>(o);
}

// ---------- LayerNorm: one block per row, D=1024, 256 threads; bf16 out ----------
template<typename TIN>
__global__ __launch_bounds__(256) void ln_kernel(const TIN* __restrict__ in,
                                                 const float* __restrict__ g,
                                                 const float* __restrict__ b,
                                                 u16* __restrict__ out)
{
    const int row = blockIdx.x, tid = threadIdx.x;
    const size_t base = (size_t)row * 1024 + tid * 4;
    float x0, x1, x2, x3;
    if constexpr (sizeof(TIN) == 4) {
        float4 v = *reinterpret_cast<const float4*>(in + base);
        x0 = v.x; x1 = v.y; x2 = v.z; x3 = v.w;
    } else {
        ushort4 v = *reinterpret_cast<const ushort4*>((const u16*)in + base);
        x0 = us2f(v.x); x1 = us2f(v.y); x2 = us2f(v.z); x3 = us2f(v.w);
    }
    float s = x0 + x1 + x2 + x3;
    float q = x0*x0 + x1*x1 + x2*x2 + x3*x3;
    #pragma unroll
    for (int o = 32; o; o >>= 1) { s += __shfl_down(s, o); q += __shfl_down(q, o); }
    __shared__ float red[8];
    if ((tid & 63) == 0) { red[tid >> 6] = s; red[4 + (tid >> 6)] = q; }
    __syncthreads();
    s = red[0] + red[1] + red[2] + red[3];
    q = red[4] + red[5] + red[6] + red[7];
    const float mu = s * (1.0f / 1024.0f);
    const float rs = rsqrtf(q * (1.0f / 1024.0f) - mu * mu + 1e-5f);
    float4 gv = *reinterpret_cast<const float4*>(g + tid * 4);
    float4 bv = *reinterpret_cast<const float4*>(b + tid * 4);
    ushort4 o4;
    o4.x = f2us((x0 - mu) * rs * gv.x + bv.x);
    o4.y = f2us((x1 - mu) * rs * gv.y + bv.y);
    o4.z = f2us((x2 - mu) * rs * gv.z + bv.z);
    o4.w = f2us((x3 - mu) * rs * gv.w + bv.w);
    *reinterpret_cast<ushort4*>(out + base) = o4;
}

// ---------- prep: B_bar concat (128x1024) and C2 concat (1024x128), bf16 ----------
__global__ __launch_bounds__(256) void prep_kernel(
    const float* __restrict__ Lre, const float* __restrict__ Lim, const float* __restrict__ lstep,
    const float* __restrict__ Bre, const float* __restrict__ Bim,
    const float* __restrict__ Cre, const float* __restrict__ Cim,
    u16* __restrict__ Bbar, u16* __restrict__ C2)
{
    const int idx = blockIdx.x * 256 + threadIdx.x;   // 0..131071
    if (idx < 65536) {
        const int p = idx >> 10, d = idx & 1023;
        const float lr = Lre[p], li = Lim[p];
        const float dt = expf(lstep[p]);
        const float er = expf(lr * dt);
        const float ar = er * cosf(li * dt), ai = er * sinf(li * dt); // Lam_bar
        const float nr = ar - 1.0f, ni = ai;
        const float den = lr * lr + li * li;
        const float cr = (nr * lr + ni * li) / den;   // coef = (Lam_bar-1)/Lam
        const float ci = (ni * lr - nr * li) / den;
        const float br = Bre[idx], bi = Bim[idx];
        Bbar[p * 1024 + d]        = f2us(cr * br - ci * bi);   // Re row p
        Bbar[(64 + p) * 1024 + d] = f2us(cr * bi + ci * br);   // Im row 64+p
    } else {
        const int i = idx - 65536;          // over (d,p): i = d*64+p
        const int d = i >> 6, p = i & 63;
        C2[d * 128 + p]      = f2us( 2.0f * Cre[i]);
        C2[d * 128 + 64 + p] = f2us(-2.0f * Cim[i]);
    }
}

// ---------- scan: one block per (b,p); chunked scan, chunk=8, 256 threads ----------
__global__ __launch_bounds__(256) void scan_kernel(
    const float* __restrict__ Bu,    // (8192,128) f32: [:,p]=re, [:,64+p]=im
    const float* __restrict__ Lre, const float* __restrict__ Lim, const float* __restrict__ lstep,
    u16* __restrict__ A2)            // (8192,128) bf16: [:,p]=Xre, [:,64+p]=Xim
{
    const int b = blockIdx.x >> 6;
    const int p = blockIdx.x & 63;
    const int t = threadIdx.x;
    const float lr = Lre[p], li = Lim[p];
    const float dt = expf(lstep[p]);
    const float er = expf(lr * dt);
    const float ar = er * cosf(li * dt), ai = er * sinf(li * dt);  // a = Lam_bar

    const size_t base = ((size_t)b * 2048 + t * 8) * 128;
    float xr[8], xi[8];
    float sr = 0.f, si = 0.f;
    #pragma unroll
    for (int i = 0; i < 8; ++i) {
        const float br = Bu[base + i * 128 + p];
        const float bi = Bu[base + i * 128 + 64 + p];
        const float nr = ar * sr - ai * si + br;
        const float ni = ar * si + ai * sr + bi;
        sr = nr; si = ni;
        xr[i] = sr; xi[i] = si;
    }
    // a^8
    float fr = ar, fi = ai;
    #pragma unroll
    for (int s = 0; s < 3; ++s) { const float t2 = fr*fr - fi*fi; fi = 2.f*fr*fi; fr = t2; }
    // Hillis-Steele over 256 chunk end-states
    __shared__ float Er[256], Ei[256];
    Er[t] = sr; Ei[t] = si;
    __syncthreads();
    float vr = sr, vi = si;
    for (int off = 1; off < 256; off <<= 1) {
        float pr = 0.f, pi = 0.f;
        if (t >= off) { pr = Er[t - off]; pi = Ei[t - off]; }
        __syncthreads();
        vr += fr * pr - fi * pi;
        vi += fr * pi + fi * pr;
        Er[t] = vr; Ei[t] = vi;
        const float nf = fr*fr - fi*fi; fi = 2.f*fr*fi; fr = nf;
        __syncthreads();
    }
    float cr = 0.f, ci = 0.f;
    if (t > 0) { cr = Er[t - 1]; ci = Ei[t - 1]; }
    // x_i += a^{i+1} * carry
    float gr = ar * cr - ai * ci, gi = ar * ci + ai * cr;
    #pragma unroll
    for (int i = 0; i < 8; ++i) {
        xr[i] += gr; xi[i] += gi;
        const float n2 = ar * gr - ai * gi; gi = ar * gi + ai * gr; gr = n2;
    }
    #pragma unroll
    for (int i = 0; i < 8; ++i) {
        const size_t m = (size_t)b * 2048 + t * 8 + i;
        A2[m * 128 + p]      = f2us(xr[i]);
        A2[m * 128 + 64 + p] = f2us(xi[i]);
    }
}

// ---------- MFMA GEMM: C = A(MxK) @ B(NxK)^T, bf16 in, single accumulator ----------
// EPI 0: f32 out (Bu). EPI 1: h = gelu(acc + dskip*fx) + fx (bf16 out).
// EPI 3: f32 out = acc + aux.
template<int BM, int BN, int WM, int WN, int EPI>
__global__ __launch_bounds__(WM * WN * 64) void gemm_kernel(
    const u16* __restrict__ A, const u16* __restrict__ B, void* __restrict__ Cout,
    const int M, const int N, const int K,
    const u16* __restrict__ aux, const float* __restrict__ dskip)
{
    constexpr int THREADS = WM * WN * 64;
    constexpr int AJ = (BM * 4) / THREADS;   // 16B slots per thread for A tile
    constexpr int BJ = (BN * 4) / THREADS;
    __shared__ u16 lsA[BM * 32];
    __shared__ u16 lsB[BN * 32];
    (void)M;

    const int tid = threadIdx.x;
    const int lane = tid & 63;
    const int wid = tid >> 6;
    const int wm = wid / WN, wn = wid % WN;
    const int m0 = blockIdx.y * BM, n0 = blockIdx.x * BN;

    f32x4 acc[4][4] = {};

    for (int k0 = 0; k0 < K; k0 += 32) {
        #pragma unroll
        for (int j = 0; j < AJ; ++j) {
            const int s = j * THREADS + tid;
            gload_lds16(A + (size_t)(m0 + (s >> 2)) * K + k0 + (s & 3) * 8,
                        lsA + (s - lane) * 8);
        }
        #pragma unroll
        for (int j = 0; j < BJ; ++j) {
            const int s = j * THREADS + tid;
            gload_lds16(B + (size_t)(n0 + (s >> 2)) * K + k0 + (s & 3) * 8,
                        lsB + (s - lane) * 8);
        }
        __syncthreads();

        v8bf af[4], bfv[4];
        #pragma unroll
        for (int f = 0; f < 4; ++f)
            af[f] = *reinterpret_cast<const v8bf*>(
                lsA + (wm * 64 + f * 16 + (lane & 15)) * 32 + (lane >> 4) * 8);
        #pragma unroll
        for (int f = 0; f < 4; ++f)
            bfv[f] = *reinterpret_cast<const v8bf*>(
                lsB + (wn * 64 + f * 16 + (lane & 15)) * 32 + (lane >> 4) * 8);
        #pragma unroll
        for (int fm = 0; fm < 4; ++fm)
            #pragma unroll
            for (int fn = 0; fn < 4; ++fn)
                acc[fm][fn] = __builtin_amdgcn_mfma_f32_16x16x32_bf16(
                    af[fm], bfv[fn], acc[fm][fn], 0, 0, 0);
        __syncthreads();
    }

    #pragma unroll
    for (int fm = 0; fm < 4; ++fm)
    #pragma unroll
    for (int fn = 0; fn < 4; ++fn)
    #pragma unroll
    for (int i = 0; i < 4; ++i) {
        const int r = m0 + wm * 64 + fm * 16 + (lane >> 4) * 4 + i;
        const int c = n0 + wn * 64 + fn * 16 + (lane & 15);
        const size_t o = (size_t)r * N + c;
        const float v = acc[fm][fn][i];
        if constexpr (EPI == 0) {
            ((float*)Cout)[o] = v;
        } else if constexpr (EPI == 1) {
            const float u = us2f(aux[o]);
            const float t = v + dskip[c] * u;
            ((u16*)Cout)[o] = f2us(gelu_f(t) + u);
        } else {
            ((float*)Cout)[o] = v + us2f(aux[o]);
        }
    }
}

// ---------- GEGLU GEMM: e2[:, n0:n0+64] = a * gelu(gate), single acc ----------
// Block: 128 M-rows x 64 output cols. B-tile: 64 a-rows (We[n0+r]) + 64 gate
// rows (We[2048+n0+r]). Waves 2x2: wn=0 accumulates a, wn=1 accumulates gate.
// Epilogue: wn=1 writes gelu(gate) bf16 into LDS (reusing staging), wn=0
// multiplies and stores.
__global__ __launch_bounds__(256) void geglu_kernel(
    const u16* __restrict__ A, const u16* __restrict__ B, u16* __restrict__ C,
    const int K)
{
    __shared__ u16 smem[128 * 32 * 2];          // lsA | lsB ; epilogue: lsG 128x64
    u16* lsA = smem;
    u16* lsB = smem + 128 * 32;

    const int tid = threadIdx.x;
    const int lane = tid & 63;
    const int wid = tid >> 6;
    const int wm = wid >> 1, wn = wid & 1;
    const int m0 = blockIdx.y * 128;
    const int n0 = blockIdx.x * 64;             // output col block

    f32x4 acc[4][4] = {};

    for (int k0 = 0; k0 < K; k0 += 32) {
        #pragma unroll
        for (int j = 0; j < 2; ++j) {
            const int s = j * 256 + tid;
            gload_lds16(A + (size_t)(m0 + (s >> 2)) * K + k0 + (s & 3) * 8,
                        lsA + (s - lane) * 8);
        }
        #pragma unroll
        for (int j = 0; j < 2; ++j) {
            const int s = j * 256 + tid;
            const int r = s >> 2;
            const int br = (r < 64) ? (n0 + r) : (2048 + n0 + (r - 64));
            gload_lds16(B + (size_t)br * K + k0 + (s & 3) * 8,
                        lsB + (s - lane) * 8);
        }
        __syncthreads();

        v8bf af[4], bfv[4];
        #pragma unroll
        for (int f = 0; f < 4; ++f)
            af[f] = *reinterpret_cast<const v8bf*>(
                lsA + (wm * 64 + f * 16 + (lane & 15)) * 32 + (lane >> 4) * 8);
        #pragma unroll
        for (int f = 0; f < 4; ++f)
            bfv[f] = *reinterpret_cast<const v8bf*>(
                lsB + (wn * 64 + f * 16 + (lane & 15)) * 32 + (lane >> 4) * 8);
        #pragma unroll
        for (int fm = 0; fm < 4; ++fm)
            #pragma unroll
            for (int fn = 0; fn < 4; ++fn)
                acc[fm][fn] = __builtin_amdgcn_mfma_f32_16x16x32_bf16(
                    af[fm], bfv[fn], acc[fm][fn], 0, 0, 0);
        __syncthreads();
    }

    // epilogue: exchange gelu(gate) through LDS
    u16* lsG = smem;                            // 128 x 64 bf16 = 16KB
    if (wn == 1) {
        #pragma unroll
        for (int fm = 0; fm < 4; ++fm)
        #pragma unroll
        for (int fn = 0; fn < 4; ++fn)
        #pragma unroll
        for (int i = 0; i < 4; ++i) {
            const int r = wm * 64 + fm * 16 + (lane >> 4) * 4 + i;
            const int c = fn * 16 + (lane & 15);
            lsG[r * 64 + c] = f2us(gelu_f(acc[fm][fn][i]));
        }
    }
    __syncthreads();
    if (wn == 0) {
        #pragma unroll
        for (int fm = 0; fm < 4; ++fm)
        #pragma unroll
        for (int fn = 0; fn < 4; ++fn)
        #pragma unroll
        for (int i = 0; i < 4; ++i) {
            const int r = wm * 64 + fm * 16 + (lane >> 4) * 4 + i;
            const int c = fn * 16 + (lane & 15);
            const float gg = us2f(lsG[r * 64 + c]);
            C[(size_t)(m0 + r) * 2048 + n0 + c] = f2us(acc[fm][fn][i] * gg);
        }
    }
}

// ---------- workspace layout (bytes) ----------
// timeline: LN1->fx | cvt->WeB,WdB | prep | G1->Bu | scan->A2 | G2->h(in d_out)
//           | LN2->fx2 | G3->e2 | G4->d_out(f32, overwrites h)
// e2 (33.55MB @ 0) aliases fx+Bu+A2 (+slack), all dead by G3.
static constexpr size_t OFF_FX  = 0;                              // bf16 16.78MB
static constexpr size_t OFF_BU  = 16777216;                       // f32   4.19MB
static constexpr size_t OFF_A2  = 20971520;                       // bf16  2.10MB
static constexpr size_t OFF_E2  = 0;                              // bf16 33.55MB (alias)
static constexpr size_t OFF_FX2 = 33554432;                       // bf16 16.78MB
static constexpr size_t OFF_BB  = 50331648;                       // bf16  0.26MB
static constexpr size_t OFF_C2  = 50593792;                       // bf16  0.26MB
static constexpr size_t OFF_WE  = 50855936;                       // bf16  8.39MB
static constexpr size_t OFF_WD  = 59244544;                       // bf16  4.19MB  (end 63.44MB)

extern "C" void kernel_launch(void* const* d_in, const int* in_sizes, int n_in,
                              void* d_out, int out_size, void* d_ws, size_t ws_size,
                              hipStream_t stream) {
    const float* x    = (const float*)d_in[0];
    const float* l1g  = (const float*)d_in[1];
    const float* l1b  = (const float*)d_in[2];
    const float* l2g  = (const float*)d_in[3];
    const float* l2b  = (const float*)d_in[4];
    const float* Lre  = (const float*)d_in[5];
    const float* Lim  = (const float*)d_in[6];
    const float* Bre  = (const float*)d_in[7];
    const float* Bim  = (const float*)d_in[8];
    const float* Cre  = (const float*)d_in[9];
    const float* Cim  = (const float*)d_in[10];
    const float* Dsk  = (const float*)d_in[11];
    const float* lst  = (const float*)d_in[12];
    const float* Wenc = (const float*)d_in[13];
    const float* Wdec = (const float*)d_in[14];
    float* out = (float*)d_out;

    char* ws = (char*)d_ws;
    u16*   fx   = (u16*)(ws + OFF_FX);
    float* Bu   = (float*)(ws + OFF_BU);
    u16*   A2   = (u16*)(ws + OFF_A2);
    u16*   e2   = (u16*)(ws + OFF_E2);
    u16*   fx2  = (u16*)(ws + OFF_FX2);
    u16*   Bbar = (u16*)(ws + OFF_BB);
    u16*   C2   = (u16*)(ws + OFF_C2);
    u16*   WeB  = (u16*)(ws + OFF_WE);
    u16*   WdB  = (u16*)(ws + OFF_WD);
    u16*   h    = (u16*)d_out;           // h (bf16) lives in d_out's first half

    // 1) fx = LN1(x)  [bf16]
    ln_kernel<float><<<8192, 256, 0, stream>>>(x, l1g, l1b, fx);
    // 1b) weight conversions + B_bar / C2 precompute
    cvt_kernel<<<2048, 256, 0, stream>>>(Wenc, WeB, 4096 * 1024);
    cvt_kernel<<<1024, 256, 0, stream>>>(Wdec, WdB, 1024 * 2048);
    prep_kernel<<<512, 256, 0, stream>>>(Lre, Lim, lst, Bre, Bim, Cre, Cim, Bbar, C2);
    // 2) Bu = fx @ Bbar^T   (8192 x 128, f32)
    gemm_kernel<64, 64, 1, 1, 0><<<dim3(2, 128), 64, 0, stream>>>(
        fx, Bbar, Bu, 8192, 128, 1024, nullptr, nullptr);
    // 3) xs scan -> A2 (bf16)
    scan_kernel<<<256, 256, 0, stream>>>(Bu, Lre, Lim, lst, A2);
    // 4) h = gelu(A2 @ C2^T + Dskip*fx) + fx  [bf16, into d_out]
    gemm_kernel<128, 128, 2, 2, 1><<<dim3(8, 64), 256, 0, stream>>>(
        A2, C2, h, 8192, 1024, 128, fx, Dsk);
    // 5) fx2 = LN2(h)  [bf16]
    ln_kernel<u16><<<8192, 256, 0, stream>>>(h, l2g, l2b, fx2);
    // 6) e2 = (fx2 @ We[:2048]^T) * gelu(fx2 @ We[2048:]^T)  [bf16]
    geglu_kernel<<<dim3(32, 64), 256, 0, stream>>>(fx2, WeB, e2, 1024);
    // 7) out = e2 @ WdB^T + fx2  [f32]
    gemm_kernel<128, 128, 2, 2, 3><<<dim3(8, 64), 256, 0, stream>>>(
        e2, WdB, out, 8192, 1024, 2048, fx2, nullptr);

    (void)in_sizes; (void)n_in; (void)out_size; (void)ws_size;
}

// Round 4
// 220.827 us; speedup vs baseline: 1.5630x; 1.2203x over previous
//
#include <hip/hip_runtime.h>
#include <hip/hip_bf16.h>
#include <math.h>

typedef unsigned short u16;
typedef __bf16 v8bf __attribute__((ext_vector_type(8)));
typedef float f32x4 __attribute__((ext_vector_type(4)));

// ---------- bf16 helpers (raw ushort representation) ----------
__device__ __forceinline__ float us2f(u16 h) {
    union { unsigned int u; float f; } v; v.u = ((unsigned int)h) << 16; return v.f;
}
__device__ __forceinline__ u16 f2us(float f) {
    union { float f; unsigned int u; } v; v.f = f;
    unsigned int r = v.u + 0x7fffu + ((v.u >> 16) & 1u);   // RNE
    return (u16)(r >> 16);
}
__device__ __forceinline__ float gelu_f(float x) {
    return 0.5f * x * (1.0f + erff(x * 0.70710678118654752f));
}
// global -> LDS direct load, 16B per lane (LDS dest is wave-uniform base + lane*16)
__device__ __forceinline__ void gload_lds16(const u16* g, u16* l) {
    auto gp = reinterpret_cast<const __attribute__((address_space(1))) unsigned int*>(
        (uintptr_t)g);
    auto lp = reinterpret_cast<__attribute__((address_space(3))) unsigned int*>(
        (uintptr_t)l);
    __builtin_amdgcn_global_load_lds(gp, lp, 16, 0, 0);
}

// ---------- f32 -> bf16 convert (n multiple of 8) ----------
__global__ __launch_bounds__(256) void cvt_kernel(const float* __restrict__ in,
                                                  u16* __restrict__ out, int n)
{
    const int i = (blockIdx.x * 256 + threadIdx.x) * 8;
    if (i >= n) return;
    float4 a = *reinterpret_cast<const float4*>(in + i);
    float4 b = *reinterpret_cast<const float4*>(in + i + 4);
    u16 o[8] = { f2us(a.x), f2us(a.y), f2us(a.z), f2us(a.w),
                 f2us(b.x), f2us(b.y), f2us(b.z), f2us(b.w) };
    *reinterpret_cast<uint4*>(out + i) = *reinterpret_cast<uint4*>(o);
}

// ---------- LayerNorm: one block per row, D=1024, 256 threads; bf16 out ----------
template<typename TIN>
__global__ __launch_bounds__(256) void ln_kernel(const TIN* __restrict__ in,
                                                 const float* __restrict__ g,
                                                 const float* __restrict__ b,
                                                 u16* __restrict__ out)
{
    const int row = blockIdx.x, tid = threadIdx.x;
    const size_t base = (size_t)row * 1024 + tid * 4;
    float x0, x1, x2, x3;
    if constexpr (sizeof(TIN) == 4) {
        float4 v = *reinterpret_cast<const float4*>(in + base);
        x0 = v.x; x1 = v.y; x2 = v.z; x3 = v.w;
    } else {
        ushort4 v = *reinterpret_cast<const ushort4*>((const u16*)in + base);
        x0 = us2f(v.x); x1 = us2f(v.y); x2 = us2f(v.z); x3 = us2f(v.w);
    }
    float s = x0 + x1 + x2 + x3;
    float q = x0*x0 + x1*x1 + x2*x2 + x3*x3;
    #pragma unroll
    for (int o = 32; o; o >>= 1) { s += __shfl_down(s, o); q += __shfl_down(q, o); }
    __shared__ float red[8];
    if ((tid & 63) == 0) { red[tid >> 6] = s; red[4 + (tid >> 6)] = q; }
    __syncthreads();
    s = red[0] + red[1] + red[2] + red[3];
    q = red[4] + red[5] + red[6] + red[7];
    const float mu = s * (1.0f / 1024.0f);
    const float rs = rsqrtf(q * (1.0f / 1024.0f) - mu * mu + 1e-5f);
    float4 gv = *reinterpret_cast<const float4*>(g + tid * 4);
    float4 bv = *reinterpret_cast<const float4*>(b + tid * 4);
    ushort4 o4;
    o4.x = f2us((x0 - mu) * rs * gv.x + bv.x);
    o4.y = f2us((x1 - mu) * rs * gv.y + bv.y);
    o4.z = f2us((x2 - mu) * rs * gv.z + bv.z);
    o4.w = f2us((x3 - mu) * rs * gv.w + bv.w);
    *reinterpret_cast<ushort4*>(out + base) = o4;
}

// ---------- prep: B_bar concat (128x1024) and C2 concat (1024x128), bf16 ----------
__global__ __launch_bounds__(256) void prep_kernel(
    const float* __restrict__ Lre, const float* __restrict__ Lim, const float* __restrict__ lstep,
    const float* __restrict__ Bre, const float* __restrict__ Bim,
    const float* __restrict__ Cre, const float* __restrict__ Cim,
    u16* __restrict__ Bbar, u16* __restrict__ C2)
{
    const int idx = blockIdx.x * 256 + threadIdx.x;   // 0..131071
    if (idx < 65536) {
        const int p = idx >> 10, d = idx & 1023;
        const float lr = Lre[p], li = Lim[p];
        const float dt = expf(lstep[p]);
        const float er = expf(lr * dt);
        const float ar = er * cosf(li * dt), ai = er * sinf(li * dt); // Lam_bar
        const float nr = ar - 1.0f, ni = ai;
        const float den = lr * lr + li * li;
        const float cr = (nr * lr + ni * li) / den;   // coef = (Lam_bar-1)/Lam
        const float ci = (ni * lr - nr * li) / den;
        const float br = Bre[idx], bi = Bim[idx];
        Bbar[p * 1024 + d]        = f2us(cr * br - ci * bi);   // Re row p
        Bbar[(64 + p) * 1024 + d] = f2us(cr * bi + ci * br);   // Im row 64+p
    } else {
        const int i = idx - 65536;          // over (d,p): i = d*64+p
        const int d = i >> 6, p = i & 63;
        C2[d * 128 + p]      = f2us( 2.0f * Cre[i]);
        C2[d * 128 + 64 + p] = f2us(-2.0f * Cim[i]);
    }
}

// ---------- scan: one block per (b,p); chunked scan, chunk=8, 256 threads ----------
__global__ __launch_bounds__(256) void scan_kernel(
    const float* __restrict__ Bu,    // (8192,128) f32: [:,p]=re, [:,64+p]=im
    const float* __restrict__ Lre, const float* __restrict__ Lim, const float* __restrict__ lstep,
    u16* __restrict__ A2)            // (8192,128) bf16: [:,p]=Xre, [:,64+p]=Xim
{
    const int b = blockIdx.x >> 6;
    const int p = blockIdx.x & 63;
    const int t = threadIdx.x;
    const float lr = Lre[p], li = Lim[p];
    const float dt = expf(lstep[p]);
    const float er = expf(lr * dt);
    const float ar = er * cosf(li * dt), ai = er * sinf(li * dt);  // a = Lam_bar

    const size_t base = ((size_t)b * 2048 + t * 8) * 128;
    float xr[8], xi[8];
    float sr = 0.f, si = 0.f;
    #pragma unroll
    for (int i = 0; i < 8; ++i) {
        const float br = Bu[base + i * 128 + p];
        const float bi = Bu[base + i * 128 + 64 + p];
        const float nr = ar * sr - ai * si + br;
        const float ni = ar * si + ai * sr + bi;
        sr = nr; si = ni;
        xr[i] = sr; xi[i] = si;
    }
    float fr = ar, fi = ai;
    #pragma unroll
    for (int s = 0; s < 3; ++s) { const float t2 = fr*fr - fi*fi; fi = 2.f*fr*fi; fr = t2; }
    __shared__ float Er[256], Ei[256];
    Er[t] = sr; Ei[t] = si;
    __syncthreads();
    float vr = sr, vi = si;
    for (int off = 1; off < 256; off <<= 1) {
        float pr = 0.f, pi = 0.f;
        if (t >= off) { pr = Er[t - off]; pi = Ei[t - off]; }
        __syncthreads();
        vr += fr * pr - fi * pi;
        vi += fr * pi + fi * pr;
        Er[t] = vr; Ei[t] = vi;
        const float nf = fr*fr - fi*fi; fi = 2.f*fr*fi; fr = nf;
        __syncthreads();
    }
    float cr = 0.f, ci = 0.f;
    if (t > 0) { cr = Er[t - 1]; ci = Ei[t - 1]; }
    float gr = ar * cr - ai * ci, gi = ar * ci + ai * cr;
    #pragma unroll
    for (int i = 0; i < 8; ++i) {
        xr[i] += gr; xi[i] += gi;
        const float n2 = ar * gr - ai * gi; gi = ar * gi + ai * gr; gr = n2;
    }
    #pragma unroll
    for (int i = 0; i < 8; ++i) {
        const size_t m = (size_t)b * 2048 + t * 8 + i;
        A2[m * 128 + p]      = f2us(xr[i]);
        A2[m * 128 + 64 + p] = f2us(xi[i]);
    }
}

// ---------- small MFMA GEMM (kept for G1 Bu: N=128), f32 out ----------
template<int BM, int BN>
__global__ __launch_bounds__(64) void gemm_small_kernel(
    const u16* __restrict__ A, const u16* __restrict__ B, float* __restrict__ Cout,
    const int N, const int K)
{
    __shared__ u16 lsA[BM * 32];
    __shared__ u16 lsB[BN * 32];
    const int tid = threadIdx.x;
    const int lane = tid & 63;
    const int m0 = blockIdx.y * BM, n0 = blockIdx.x * BN;
    f32x4 acc[4][4] = {};
    for (int k0 = 0; k0 < K; k0 += 32) {
        #pragma unroll
        for (int j = 0; j < 4; ++j) {
            const int s = j * 64 + tid;
            gload_lds16(A + (size_t)(m0 + (s >> 2)) * K + k0 + (s & 3) * 8,
                        lsA + (s - lane) * 8);
            gload_lds16(B + (size_t)(n0 + (s >> 2)) * K + k0 + (s & 3) * 8,
                        lsB + (s - lane) * 8);
        }
        __syncthreads();
        v8bf af[4], bfv[4];
        #pragma unroll
        for (int f = 0; f < 4; ++f)
            af[f] = *reinterpret_cast<const v8bf*>(
                lsA + (f * 16 + (lane & 15)) * 32 + (lane >> 4) * 8);
        #pragma unroll
        for (int f = 0; f < 4; ++f)
            bfv[f] = *reinterpret_cast<const v8bf*>(
                lsB + (f * 16 + (lane & 15)) * 32 + (lane >> 4) * 8);
        #pragma unroll
        for (int fm = 0; fm < 4; ++fm)
            #pragma unroll
            for (int fn = 0; fn < 4; ++fn)
                acc[fm][fn] = __builtin_amdgcn_mfma_f32_16x16x32_bf16(
                    af[fm], bfv[fn], acc[fm][fn], 0, 0, 0);
        __syncthreads();
    }
    #pragma unroll
    for (int fm = 0; fm < 4; ++fm)
    #pragma unroll
    for (int fn = 0; fn < 4; ++fn)
    #pragma unroll
    for (int i = 0; i < 4; ++i) {
        const int r = m0 + fm * 16 + (lane >> 4) * 4 + i;
        const int c = n0 + fn * 16 + (lane & 15);
        Cout[(size_t)r * N + c] = acc[fm][fn][i];
    }
}

// ================= 8-phase 256-tile GEMM (T2+T3+T4+T5, T1 swizzle) =================
// C = A(Mx K) @ B(rows x K)^T with 256x128-out tiles, BK=64, 512 thr (2Mx4N waves).
// EPI 1: h = gelu(acc + dskip*fx) + fx (bf16). EPI 2: GEGLU dual-B (BROWS=256:
// rows 0-127 = a = Wenc[n0+rb], 128-255 = gate = Wenc[NO+n0+rb-128]); out bf16.
// EPI 3: f32 out = acc + aux.
// LDS tile layout: rows of 64 bf16 (128B); 16B slot s of row r stored at
// physical slot s ^ (r&7)  (XOR swizzle, applied on BOTH the pre-swizzled
// global source for global_load_lds and the ds_read address).
template<bool GLU>
__device__ __forceinline__ void stage_half(u16* ldsbuf,
    const u16* __restrict__ A, const u16* __restrict__ Bm,
    int half, int tile, int m0, int n0, int K, int NO, int wid, int lane)
{
    const int k0 = tile * 64;
    #pragma unroll
    for (int j = 0; j < 2; ++j) {
        const int chunk = wid * 2 + j;                   // 0..15
        const int rloc  = chunk * 8 + (lane >> 3);       // row within half
        const int sslot = (lane & 7) ^ ((lane >> 3) & 7);
        const u16* src;
        int ldsrow0;
        if (half < 2) {
            ldsrow0 = half * 128 + chunk * 8;
            src = A + (size_t)(m0 + half * 128 + rloc) * K + k0 + sslot * 8;
        } else {
            const int rb = (half - 2) * 128 + rloc;
            ldsrow0 = 256 + (half - 2) * 128 + chunk * 8;
            const int grow = GLU ? ((half == 2) ? (n0 + rb) : (NO + n0 + rb - 128))
                                 : (n0 + rb);
            src = Bm + (size_t)grow * K + k0 + sslot * 8;
        }
        gload_lds16(src, ldsbuf + ldsrow0 * 64);
    }
}

template<int BROWS, int EPI, int NBX>
__global__ __launch_bounds__(512, 2) void gemm8p_kernel(
    const u16* __restrict__ A, const u16* __restrict__ Bm, void* __restrict__ Cout,
    const int K, const int NO, const int NT,
    const u16* __restrict__ aux, const float* __restrict__ dskip)
{
    constexpr bool GLU = (EPI == 2);
    __shared__ u16 lds[2][(256 + BROWS) * 64];

    const int tid  = threadIdx.x;
    const int lane = tid & 63;
    const int wid  = tid >> 6;
    const int wm   = wid >> 2;           // 0..1
    const int wn   = wid & 3;            // 0..3
    const int l15 = lane & 15, lg = lane >> 4, l7 = lane & 7;

    // T1: XCD-aware bijective block swizzle (nwg = NBX*32, always % 8 == 0)
    const int bid = blockIdx.x;
    const int swz = (bid & 7) * (NBX * 4) + (bid >> 3);
    const int by = swz / NBX, bx = swz % NBX;
    const int m0 = by * 256, n0 = bx * 128;

    f32x4 accA[8][2] = {};
    f32x4 accG[8][2] = {};               // unused (DCE'd) unless GLU

    // stage schedule per phase ph=0..7 (derived from region last-read phases):
    // p1,p2: A0,A1(2i+1) [skip i==0]; p3,p4: B0,B1(2i+2);
    // p5,p6: A0,A1(2i+2); p7,p8: B0,B1(2i+3)
    constexpr int S_HALF[8] = {0, 1, 2, 3, 0, 1, 2, 3};
    constexpr int S_OFS [8] = {1, 1, 2, 2, 2, 2, 3, 3};

    // prologue: stage tiles 0 and 1 fully, drain, sync
    #pragma unroll
    for (int t = 0; t < 2; ++t)
        #pragma unroll
        for (int h = 0; h < (GLU ? 4 : 3); ++h)
            stage_half<GLU>((u16*)lds[t], A, Bm, h, t, m0, n0, K, NO, wid, lane);
    asm volatile("s_waitcnt vmcnt(0)" ::: "memory");
    __builtin_amdgcn_s_barrier();

    const int NI = NT >> 1;
    for (int i = 0; i < NI; ++i) {
        #pragma unroll
        for (int hb = 0; hb < 2; ++hb) {          // tile 2i+hb from lds[hb]
            const u16* cb = (const u16*)lds[hb];
            v8bf bf[2][2][2];                      // [cf][ag][kk]
            #pragma unroll
            for (int p = 0; p < 4; ++p) {
                // ---- issue ds_reads ----
                v8bf af[2][2];
                #pragma unroll
                for (int j = 0; j < 2; ++j) {
                    const int row = wm * 128 + (p * 2 + j) * 16 + l15;
                    #pragma unroll
                    for (int kk = 0; kk < 2; ++kk) {
                        const int phys = (kk * 4 + lg) ^ l7;
                        af[j][kk] = *reinterpret_cast<const v8bf*>(
                            cb + row * 64 + phys * 8);
                    }
                }
                if (p == 0) {
                    #pragma unroll
                    for (int cf = 0; cf < 2; ++cf)
                    #pragma unroll
                    for (int ag = 0; ag < (GLU ? 2 : 1); ++ag)
                    #pragma unroll
                    for (int kk = 0; kk < 2; ++kk) {
                        const int rb = ag * 128 + wn * 32 + cf * 16 + l15;
                        const int phys = (kk * 4 + lg) ^ l7;
                        bf[cf][ag][kk] = *reinterpret_cast<const v8bf*>(
                            cb + (256 + rb) * 64 + phys * 8);
                    }
                }
                // ---- issue prefetch stage ----
                {
                    const int ph = hb * 4 + p;
                    const int ofs = S_OFS[ph], sh = S_HALF[ph];
                    const int tgt = 2 * i + ofs;
                    bool dost = (ofs == 1) ? (i > 0) : (tgt < NT);
                    if (!GLU && sh == 3) dost = false;
                    if (dost)
                        stage_half<GLU>((u16*)lds[tgt & 1], A, Bm, sh, tgt,
                                        m0, n0, K, NO, wid, lane);
                }
                __builtin_amdgcn_s_barrier();
                asm volatile("s_waitcnt lgkmcnt(0)" ::: "memory");
                __builtin_amdgcn_sched_barrier(0);
                __builtin_amdgcn_s_setprio(1);
                #pragma unroll
                for (int j = 0; j < 2; ++j) {
                    const int mf = p * 2 + j;
                    #pragma unroll
                    for (int cf = 0; cf < 2; ++cf)
                    #pragma unroll
                    for (int kk = 0; kk < 2; ++kk) {
                        accA[mf][cf] = __builtin_amdgcn_mfma_f32_16x16x32_bf16(
                            af[j][kk], bf[cf][0][kk], accA[mf][cf], 0, 0, 0);
                        if constexpr (GLU)
                            accG[mf][cf] = __builtin_amdgcn_mfma_f32_16x16x32_bf16(
                                af[j][kk], bf[cf][1][kk], accG[mf][cf], 0, 0, 0);
                    }
                }
                __builtin_amdgcn_s_setprio(0);
                if (p == 3) {
                    // counted vmcnt: keep only the B-halves staged this half-iter
                    const int keept = 2 * i + 2 + hb;
                    if (keept < NT) {
                        if constexpr (GLU)
                            asm volatile("s_waitcnt vmcnt(4)" ::: "memory");
                        else
                            asm volatile("s_waitcnt vmcnt(2)" ::: "memory");
                    } else {
                        asm volatile("s_waitcnt vmcnt(0)" ::: "memory");
                    }
                }
                __builtin_amdgcn_s_barrier();
            }
        }
    }

    // ---- epilogue ----
    #pragma unroll
    for (int mf = 0; mf < 8; ++mf)
    #pragma unroll
    for (int cf = 0; cf < 2; ++cf)
    #pragma unroll
    for (int q = 0; q < 4; ++q) {
        const int r = m0 + wm * 128 + mf * 16 + lg * 4 + q;
        const int c = n0 + wn * 32 + cf * 16 + l15;
        const size_t o = (size_t)r * NO + c;
        const float v = accA[mf][cf][q];
        if constexpr (EPI == 2) {
            ((u16*)Cout)[o] = f2us(v * gelu_f(accG[mf][cf][q]));
        } else if constexpr (EPI == 1) {
            const float u = us2f(aux[o]);
            const float t2 = v + dskip[c] * u;
            ((u16*)Cout)[o] = f2us(gelu_f(t2) + u);
        } else {
            ((float*)Cout)[o] = v + us2f(aux[o]);
        }
    }
}

// ---------- workspace layout (bytes) ----------
static constexpr size_t OFF_FX  = 0;                              // bf16 16.78MB
static constexpr size_t OFF_BU  = 16777216;                       // f32   4.19MB
static constexpr size_t OFF_A2  = 20971520;                       // bf16  2.10MB
static constexpr size_t OFF_E2  = 0;                              // bf16 33.55MB (alias)
static constexpr size_t OFF_FX2 = 33554432;                       // bf16 16.78MB
static constexpr size_t OFF_BB  = 50331648;                       // bf16  0.26MB
static constexpr size_t OFF_C2  = 50593792;                       // bf16  0.26MB
static constexpr size_t OFF_WE  = 50855936;                       // bf16  8.39MB
static constexpr size_t OFF_WD  = 59244544;                       // bf16  4.19MB  (end 63.44MB)

extern "C" void kernel_launch(void* const* d_in, const int* in_sizes, int n_in,
                              void* d_out, int out_size, void* d_ws, size_t ws_size,
                              hipStream_t stream) {
    const float* x    = (const float*)d_in[0];
    const float* l1g  = (const float*)d_in[1];
    const float* l1b  = (const float*)d_in[2];
    const float* l2g  = (const float*)d_in[3];
    const float* l2b  = (const float*)d_in[4];
    const float* Lre  = (const float*)d_in[5];
    const float* Lim  = (const float*)d_in[6];
    const float* Bre  = (const float*)d_in[7];
    const float* Bim  = (const float*)d_in[8];
    const float* Cre  = (const float*)d_in[9];
    const float* Cim  = (const float*)d_in[10];
    const float* Dsk  = (const float*)d_in[11];
    const float* lst  = (const float*)d_in[12];
    const float* Wenc = (const float*)d_in[13];
    const float* Wdec = (const float*)d_in[14];
    float* out = (float*)d_out;

    char* ws = (char*)d_ws;
    u16*   fx   = (u16*)(ws + OFF_FX);
    float* Bu   = (float*)(ws + OFF_BU);
    u16*   A2   = (u16*)(ws + OFF_A2);
    u16*   e2   = (u16*)(ws + OFF_E2);
    u16*   fx2  = (u16*)(ws + OFF_FX2);
    u16*   Bbar = (u16*)(ws + OFF_BB);
    u16*   C2   = (u16*)(ws + OFF_C2);
    u16*   WeB  = (u16*)(ws + OFF_WE);
    u16*   WdB  = (u16*)(ws + OFF_WD);
    u16*   h    = (u16*)d_out;           // h (bf16) lives in d_out's first half

    // 1) fx = LN1(x)  [bf16]
    ln_kernel<float><<<8192, 256, 0, stream>>>(x, l1g, l1b, fx);
    // 1b) weight conversions + B_bar / C2 precompute
    cvt_kernel<<<2048, 256, 0, stream>>>(Wenc, WeB, 4096 * 1024);
    cvt_kernel<<<1024, 256, 0, stream>>>(Wdec, WdB, 1024 * 2048);
    prep_kernel<<<512, 256, 0, stream>>>(Lre, Lim, lst, Bre, Bim, Cre, Cim, Bbar, C2);
    // 2) Bu = fx @ Bbar^T   (8192 x 128, f32)
    gemm_small_kernel<64, 64><<<dim3(2, 128), 64, 0, stream>>>(
        fx, Bbar, Bu, 128, 1024);
    // 3) xs scan -> A2 (bf16)
    scan_kernel<<<256, 256, 0, stream>>>(Bu, Lre, Lim, lst, A2);
    // 4) h = gelu(A2 @ C2^T + Dskip*fx) + fx  [bf16, into d_out]
    gemm8p_kernel<128, 1, 8><<<256, 512, 0, stream>>>(
        A2, C2, h, 128, 1024, 2, fx, Dsk);
    // 5) fx2 = LN2(h)  [bf16]
    ln_kernel<u16><<<8192, 256, 0, stream>>>(h, l2g, l2b, fx2);
    // 6) e2 = (fx2 @ We[:2048]^T) * gelu(fx2 @ We[2048:]^T)  [bf16]
    gemm8p_kernel<256, 2, 16><<<512, 512, 0, stream>>>(
        fx2, WeB, e2, 1024, 2048, 16, nullptr, nullptr);
    // 7) out = e2 @ WdB^T + fx2  [f32]
    gemm8p_kernel<128, 3, 8><<<256, 512, 0, stream>>>(
        e2, WdB, out, 2048, 1024, 32, fx2, nullptr);

    (void)in_sizes; (void)n_in; (void)out_size; (void)ws_size;
}

// Round 5
// 219.189 us; speedup vs baseline: 1.5747x; 1.0075x over previous
//
#include <hip/hip_runtime.h>
#include <hip/hip_bf16.h>
#include <math.h>

typedef unsigned short u16;
typedef __bf16 v8bf __attribute__((ext_vector_type(8)));
typedef float f32x4 __attribute__((ext_vector_type(4)));

// ---------- bf16 helpers ----------
__device__ __forceinline__ float us2f(u16 h) {
    union { unsigned int u; float f; } v; v.u = ((unsigned int)h) << 16; return v.f;
}
__device__ __forceinline__ u16 f2us(float f) {
    union { float f; unsigned int u; } v; v.f = f;
    unsigned int r = v.u + 0x7fffu + ((v.u >> 16) & 1u);   // RNE
    return (u16)(r >> 16);
}
__device__ __forceinline__ float gelu_f(float x) {
    return 0.5f * x * (1.0f + erff(x * 0.70710678118654752f));
}
__device__ __forceinline__ void gload_lds16(const u16* g, u16* l) {
    auto gp = reinterpret_cast<const __attribute__((address_space(1))) unsigned int*>(
        (uintptr_t)g);
    auto lp = reinterpret_cast<__attribute__((address_space(3))) unsigned int*>(
        (uintptr_t)l);
    __builtin_amdgcn_global_load_lds(gp, lp, 16, 0, 0);
}

// ---------- fused prep: cvt Wenc, cvt Wdec, Bbar/C2 ----------
__global__ __launch_bounds__(256) void prepall_kernel(
    const float* __restrict__ Wenc, u16* __restrict__ WeB,
    const float* __restrict__ Wdec, u16* __restrict__ WdB,
    const float* __restrict__ Lre, const float* __restrict__ Lim,
    const float* __restrict__ lstep,
    const float* __restrict__ Bre, const float* __restrict__ Bim,
    const float* __restrict__ Cre, const float* __restrict__ Cim,
    u16* __restrict__ Bbar, u16* __restrict__ C2)
{
    const int b = blockIdx.x, tid = threadIdx.x;
    if (b < 3072) {
        const float* in = (b < 2048) ? Wenc : Wdec;
        u16* outp = (b < 2048) ? WeB : WdB;
        const int i = (b < 2048 ? b : b - 2048) * 2048 + tid * 8;
        float4 a = *reinterpret_cast<const float4*>(in + i);
        float4 c = *reinterpret_cast<const float4*>(in + i + 4);
        u16 o[8] = { f2us(a.x), f2us(a.y), f2us(a.z), f2us(a.w),
                     f2us(c.x), f2us(c.y), f2us(c.z), f2us(c.w) };
        *reinterpret_cast<uint4*>(outp + i) = *reinterpret_cast<uint4*>(o);
        return;
    }
    const int idx = (b - 3072) * 256 + tid;   // 0..131071
    if (idx < 65536) {
        const int p = idx >> 10, d = idx & 1023;
        const float lr = Lre[p], li = Lim[p];
        const float dt = expf(lstep[p]);
        const float er = expf(lr * dt);
        const float ar = er * cosf(li * dt), ai = er * sinf(li * dt);
        const float nr = ar - 1.0f, ni = ai;
        const float den = lr * lr + li * li;
        const float cr = (nr * lr + ni * li) / den;
        const float ci = (ni * lr - nr * li) / den;
        const float br = Bre[idx], bi = Bim[idx];
        Bbar[p * 1024 + d]        = f2us(cr * br - ci * bi);
        Bbar[(64 + p) * 1024 + d] = f2us(cr * bi + ci * br);
    } else {
        const int i = idx - 65536;
        const int d = i >> 6, p = i & 63;
        C2[d * 128 + p]      = f2us( 2.0f * Cre[i]);
        C2[d * 128 + 64 + p] = f2us(-2.0f * Cim[i]);
    }
}

// ---------- LayerNorm ----------
template<typename TIN>
__global__ __launch_bounds__(256) void ln_kernel(const TIN* __restrict__ in,
                                                 const float* __restrict__ g,
                                                 const float* __restrict__ b,
                                                 u16* __restrict__ out)
{
    const int row = blockIdx.x, tid = threadIdx.x;
    const size_t base = (size_t)row * 1024 + tid * 4;
    float x0, x1, x2, x3;
    if constexpr (sizeof(TIN) == 4) {
        float4 v = *reinterpret_cast<const float4*>(in + base);
        x0 = v.x; x1 = v.y; x2 = v.z; x3 = v.w;
    } else {
        ushort4 v = *reinterpret_cast<const ushort4*>((const u16*)in + base);
        x0 = us2f(v.x); x1 = us2f(v.y); x2 = us2f(v.z); x3 = us2f(v.w);
    }
    float s = x0 + x1 + x2 + x3;
    float q = x0*x0 + x1*x1 + x2*x2 + x3*x3;
    #pragma unroll
    for (int o = 32; o; o >>= 1) { s += __shfl_down(s, o); q += __shfl_down(q, o); }
    __shared__ float red[8];
    if ((tid & 63) == 0) { red[tid >> 6] = s; red[4 + (tid >> 6)] = q; }
    __syncthreads();
    s = red[0] + red[1] + red[2] + red[3];
    q = red[4] + red[5] + red[6] + red[7];
    const float mu = s * (1.0f / 1024.0f);
    const float rs = rsqrtf(q * (1.0f / 1024.0f) - mu * mu + 1e-5f);
    float4 gv = *reinterpret_cast<const float4*>(g + tid * 4);
    float4 bv = *reinterpret_cast<const float4*>(b + tid * 4);
    ushort4 o4;
    o4.x = f2us((x0 - mu) * rs * gv.x + bv.x);
    o4.y = f2us((x1 - mu) * rs * gv.y + bv.y);
    o4.z = f2us((x2 - mu) * rs * gv.z + bv.z);
    o4.w = f2us((x3 - mu) * rs * gv.w + bv.w);
    *reinterpret_cast<ushort4*>(out + base) = o4;
}

// ---------- scan ----------
__global__ __launch_bounds__(256) void scan_kernel(
    const float* __restrict__ Bu,
    const float* __restrict__ Lre, const float* __restrict__ Lim,
    const float* __restrict__ lstep,
    u16* __restrict__ A2)
{
    const int b = blockIdx.x >> 6;
    const int p = blockIdx.x & 63;
    const int t = threadIdx.x;
    const float lr = Lre[p], li = Lim[p];
    const float dt = expf(lstep[p]);
    const float er = expf(lr * dt);
    const float ar = er * cosf(li * dt), ai = er * sinf(li * dt);

    const size_t base = ((size_t)b * 2048 + t * 8) * 128;
    float xr[8], xi[8];
    float sr = 0.f, si = 0.f;
    #pragma unroll
    for (int i = 0; i < 8; ++i) {
        const float br = Bu[base + i * 128 + p];
        const float bi = Bu[base + i * 128 + 64 + p];
        const float nr = ar * sr - ai * si + br;
        const float ni = ar * si + ai * sr + bi;
        sr = nr; si = ni;
        xr[i] = sr; xi[i] = si;
    }
    float fr = ar, fi = ai;
    #pragma unroll
    for (int s = 0; s < 3; ++s) { const float t2 = fr*fr - fi*fi; fi = 2.f*fr*fi; fr = t2; }
    __shared__ float Er[256], Ei[256];
    Er[t] = sr; Ei[t] = si;
    __syncthreads();
    float vr = sr, vi = si;
    for (int off = 1; off < 256; off <<= 1) {
        float pr = 0.f, pi = 0.f;
        if (t >= off) { pr = Er[t - off]; pi = Ei[t - off]; }
        __syncthreads();
        vr += fr * pr - fi * pi;
        vi += fr * pi + fi * pr;
        Er[t] = vr; Ei[t] = vi;
        const float nf = fr*fr - fi*fi; fi = 2.f*fr*fi; fr = nf;
        __syncthreads();
    }
    float cr = 0.f, ci = 0.f;
    if (t > 0) { cr = Er[t - 1]; ci = Ei[t - 1]; }
    float gr = ar * cr - ai * ci, gi = ar * ci + ai * cr;
    #pragma unroll
    for (int i = 0; i < 8; ++i) {
        xr[i] += gr; xi[i] += gi;
        const float n2 = ar * gr - ai * gi; gi = ar * gi + ai * gr; gr = n2;
    }
    #pragma unroll
    for (int i = 0; i < 8; ++i) {
        const size_t m = (size_t)b * 2048 + t * 8 + i;
        A2[m * 128 + p]      = f2us(xr[i]);
        A2[m * 128 + 64 + p] = f2us(xi[i]);
    }
}

// ---------- small MFMA GEMM (G1 Bu) ----------
template<int BM, int BN>
__global__ __launch_bounds__(64) void gemm_small_kernel(
    const u16* __restrict__ A, const u16* __restrict__ B, float* __restrict__ Cout,
    const int N, const int K)
{
    __shared__ u16 lsA[BM * 32];
    __shared__ u16 lsB[BN * 32];
    const int tid = threadIdx.x;
    const int lane = tid & 63;
    const int m0 = blockIdx.y * BM, n0 = blockIdx.x * BN;
    f32x4 acc[4][4] = {};
    for (int k0 = 0; k0 < K; k0 += 32) {
        #pragma unroll
        for (int j = 0; j < 4; ++j) {
            const int s = j * 64 + tid;
            gload_lds16(A + (size_t)(m0 + (s >> 2)) * K + k0 + (s & 3) * 8,
                        lsA + (s - lane) * 8);
            gload_lds16(B + (size_t)(n0 + (s >> 2)) * K + k0 + (s & 3) * 8,
                        lsB + (s - lane) * 8);
        }
        __syncthreads();
        v8bf af[4], bfv[4];
        #pragma unroll
        for (int f = 0; f < 4; ++f)
            af[f] = *reinterpret_cast<const v8bf*>(
                lsA + (f * 16 + (lane & 15)) * 32 + (lane >> 4) * 8);
        #pragma unroll
        for (int f = 0; f < 4; ++f)
            bfv[f] = *reinterpret_cast<const v8bf*>(
                lsB + (f * 16 + (lane & 15)) * 32 + (lane >> 4) * 8);
        #pragma unroll
        for (int fm = 0; fm < 4; ++fm)
            #pragma unroll
            for (int fn = 0; fn < 4; ++fn)
                acc[fm][fn] = __builtin_amdgcn_mfma_f32_16x16x32_bf16(
                    af[fm], bfv[fn], acc[fm][fn], 0, 0, 0);
        __syncthreads();
    }
    #pragma unroll
    for (int fm = 0; fm < 4; ++fm)
    #pragma unroll
    for (int fn = 0; fn < 4; ++fn)
    #pragma unroll
    for (int i = 0; i < 4; ++i) {
        const int r = m0 + fm * 16 + (lane >> 4) * 4 + i;
        const int c = n0 + fn * 16 + (lane & 15);
        Cout[(size_t)r * N + c] = acc[fm][fn][i];
    }
}

// ================= shared pieces for the pipelined GEMMs =================
// LDS tile: rows of 64 bf16 (128B). 16B slot s of row r at phys slot s^(r&7).
// Stage covers 128 rows per stream: chunk=wid*2+j (8 rows each), 8 lanes/row.
#define BAR_MMA_BEGIN \
    __builtin_amdgcn_s_barrier(); \
    asm volatile("s_waitcnt lgkmcnt(0)" ::: "memory"); \
    __builtin_amdgcn_sched_barrier(0); \
    __builtin_amdgcn_s_setprio(1);
#define MMA_END  __builtin_amdgcn_s_setprio(0);
#define ENDBAR   __builtin_amdgcn_s_barrier();
#define VMK(n)   asm volatile("s_waitcnt vmcnt(" #n ")" ::: "memory");

// STAGE: stream s (compile-time), dest buffer index bi (0/1). 2 gloads + advance.
#define STAGE(s, bi) do { \
    u16* d0_ = lds + (bi) * BUFE + ((s) * 128 + (wid * 2 + 0) * 8) * 64; \
    u16* d1_ = lds + (bi) * BUFE + ((s) * 128 + (wid * 2 + 1) * 8) * 64; \
    gload_lds16(pS[s][0], d0_); gload_lds16(pS[s][1], d1_); \
    pS[s][0] += 64; pS[s][1] += 64; } while (0)

// ---------------- GEGLU 8-phase kernel (EPI2) ----------------
template<int MFB>
__device__ __forceinline__ void glu_read_a(const u16* cb, int wm, int l15, int lg,
                                           int l7, v8bf (&af)[2][2])
{
    #pragma unroll
    for (int j = 0; j < 2; ++j) {
        const int row = wm * 128 + (MFB + j) * 16 + l15;
        #pragma unroll
        for (int kk = 0; kk < 2; ++kk)
            af[j][kk] = *reinterpret_cast<const v8bf*>(
                cb + row * 64 + (((kk * 4 + lg) ^ l7) * 8));
    }
}
__device__ __forceinline__ void glu_read_b(const u16* cb, int wn, int l15, int lg,
                                           int l7, v8bf (&bf)[2][2][2])
{
    #pragma unroll
    for (int cf = 0; cf < 2; ++cf)
    #pragma unroll
    for (int ag = 0; ag < 2; ++ag)
    #pragma unroll
    for (int kk = 0; kk < 2; ++kk) {
        const int rb = ag * 128 + wn * 32 + cf * 16 + l15;
        bf[cf][ag][kk] = *reinterpret_cast<const v8bf*>(
            cb + (256 + rb) * 64 + (((kk * 4 + lg) ^ l7) * 8));
    }
}
template<int MFB>
__device__ __forceinline__ void glu_mma(const v8bf (&af)[2][2], const v8bf (&bf)[2][2][2],
                                        f32x4 (&accA)[8][2], f32x4 (&accG)[8][2])
{
    #pragma unroll
    for (int j = 0; j < 2; ++j)
    #pragma unroll
    for (int cf = 0; cf < 2; ++cf)
    #pragma unroll
    for (int kk = 0; kk < 2; ++kk) {
        accA[MFB + j][cf] = __builtin_amdgcn_mfma_f32_16x16x32_bf16(
            af[j][kk], bf[cf][0][kk], accA[MFB + j][cf], 0, 0, 0);
        accG[MFB + j][cf] = __builtin_amdgcn_mfma_f32_16x16x32_bf16(
            af[j][kk], bf[cf][1][kk], accG[MFB + j][cf], 0, 0, 0);
    }
}

template<int NBX>
__global__ __launch_bounds__(512, 2) void geglu8p_kernel(
    const u16* __restrict__ A, const u16* __restrict__ Bm, u16* __restrict__ Cout,
    const int K, const int NO, const int NT)
{
    constexpr int BUFE = 512 * 64;
    __shared__ u16 lds[2 * BUFE];
    const int tid = threadIdx.x, lane = tid & 63, wid = tid >> 6;
    const int wm = wid >> 2, wn = wid & 3;
    const int l15 = lane & 15, lg = lane >> 4, l7 = lane & 7;
    const int bid = blockIdx.x;
    const int swz = (bid & 7) * (NBX * 4) + (bid >> 3);
    const int by = swz / NBX, bx = swz % NBX;
    const int m0 = by * 256, n0 = bx * 128;

    // staging src pointers: streams 0=A0,1=A1,2=B(a),3=B(gate)
    const int rl = lane >> 3;
    const int scol = ((lane & 7) ^ rl) * 8;
    const u16* pS[4][2];
    #pragma unroll
    for (int j = 0; j < 2; ++j) {
        const int rloc = (wid * 2 + j) * 8 + rl;
        pS[0][j] = A  + (size_t)(m0 + rloc)       * K + scol;
        pS[1][j] = A  + (size_t)(m0 + 128 + rloc) * K + scol;
        pS[2][j] = Bm + (size_t)(n0 + rloc)       * K + scol;
        pS[3][j] = Bm + (size_t)(NO + n0 + rloc)  * K + scol;
    }

    f32x4 accA[8][2] = {};
    f32x4 accG[8][2] = {};

    // prologue: tiles 0,1 fully
    #pragma unroll
    for (int t = 0; t < 2; ++t) {
        STAGE(0, t); STAGE(1, t); STAGE(2, t); STAGE(3, t);
    }
    VMK(0);
    __builtin_amdgcn_s_barrier();

    const int NI = NT >> 1;
    for (int i = 0; i < NI; ++i) {
        const bool s1 = (i > 0);
        const bool s2 = (2 * i + 2 < NT);
        const bool s3 = (2 * i + 3 < NT);
        // ===== hb0: tile 2i from buf0 =====
        {
            const u16* cb = lds;
            v8bf bf[2][2][2];
            v8bf af[2][2];
            glu_read_a<0>(cb, wm, l15, lg, l7, af);
            glu_read_b(cb, wn, l15, lg, l7, bf);
            if (s1) STAGE(0, 1);
            BAR_MMA_BEGIN; glu_mma<0>(af, bf, accA, accG); MMA_END; ENDBAR;
            glu_read_a<2>(cb, wm, l15, lg, l7, af);
            if (s1) STAGE(1, 1);
            BAR_MMA_BEGIN; glu_mma<2>(af, bf, accA, accG); MMA_END; ENDBAR;
            glu_read_a<4>(cb, wm, l15, lg, l7, af);
            if (s2) STAGE(2, 0);
            BAR_MMA_BEGIN; glu_mma<4>(af, bf, accA, accG); MMA_END; ENDBAR;
            glu_read_a<6>(cb, wm, l15, lg, l7, af);
            if (s2) STAGE(3, 0);
            BAR_MMA_BEGIN; glu_mma<6>(af, bf, accA, accG); MMA_END;
            if (s2) { VMK(4); } else { VMK(0); }
            ENDBAR;
        }
        // ===== hb1: tile 2i+1 from buf1 =====
        {
            const u16* cb = lds + BUFE;
            v8bf bf[2][2][2];
            v8bf af[2][2];
            glu_read_a<0>(cb, wm, l15, lg, l7, af);
            glu_read_b(cb, wn, l15, lg, l7, bf);
            if (s2) STAGE(0, 0);
            BAR_MMA_BEGIN; glu_mma<0>(af, bf, accA, accG); MMA_END; ENDBAR;
            glu_read_a<2>(cb, wm, l15, lg, l7, af);
            if (s2) STAGE(1, 0);
            BAR_MMA_BEGIN; glu_mma<2>(af, bf, accA, accG); MMA_END; ENDBAR;
            glu_read_a<4>(cb, wm, l15, lg, l7, af);
            if (s3) STAGE(2, 1);
            BAR_MMA_BEGIN; glu_mma<4>(af, bf, accA, accG); MMA_END; ENDBAR;
            glu_read_a<6>(cb, wm, l15, lg, l7, af);
            if (s3) STAGE(3, 1);
            BAR_MMA_BEGIN; glu_mma<6>(af, bf, accA, accG); MMA_END;
            if (s3) { VMK(4); } else { VMK(0); }
            ENDBAR;
        }
    }

    #pragma unroll
    for (int mf = 0; mf < 8; ++mf)
    #pragma unroll
    for (int cf = 0; cf < 2; ++cf)
    #pragma unroll
    for (int q = 0; q < 4; ++q) {
        const int r = m0 + wm * 128 + mf * 16 + lg * 4 + q;
        const int c = n0 + wn * 32 + cf * 16 + l15;
        Cout[(size_t)r * NO + c] = f2us(accA[mf][cf][q] * gelu_f(accG[mf][cf][q]));
    }
}

// ---------------- 4-fat-phase GEMM (EPI 1 / 3) ----------------
template<int MFB, bool READB>
__device__ __forceinline__ void p4_read(const u16* cb, int wm, int wn, int l15,
                                        int lg, int l7, v8bf (&af)[4][2], v8bf (&bf)[2][2])
{
    #pragma unroll
    for (int j = 0; j < 4; ++j) {
        const int row = wm * 128 + (MFB + j) * 16 + l15;
        #pragma unroll
        for (int kk = 0; kk < 2; ++kk)
            af[j][kk] = *reinterpret_cast<const v8bf*>(
                cb + row * 64 + (((kk * 4 + lg) ^ l7) * 8));
    }
    if constexpr (READB) {
        #pragma unroll
        for (int cf = 0; cf < 2; ++cf)
        #pragma unroll
        for (int kk = 0; kk < 2; ++kk) {
            const int rb = wn * 32 + cf * 16 + l15;
            bf[cf][kk] = *reinterpret_cast<const v8bf*>(
                cb + (256 + rb) * 64 + (((kk * 4 + lg) ^ l7) * 8));
        }
    }
}
template<int MFB>
__device__ __forceinline__ void p4_mma(const v8bf (&af)[4][2], const v8bf (&bf)[2][2],
                                       f32x4 (&accA)[8][2])
{
    #pragma unroll
    for (int j = 0; j < 4; ++j)
    #pragma unroll
    for (int cf = 0; cf < 2; ++cf)
    #pragma unroll
    for (int kk = 0; kk < 2; ++kk)
        accA[MFB + j][cf] = __builtin_amdgcn_mfma_f32_16x16x32_bf16(
            af[j][kk], bf[cf][kk], accA[MFB + j][cf], 0, 0, 0);
}

template<int EPI, int NBX>
__global__ __launch_bounds__(512, 2) void gemm4p_kernel(
    const u16* __restrict__ A, const u16* __restrict__ Bm, void* __restrict__ Cout,
    const int K, const int NO, const int NT,
    const u16* __restrict__ aux, const float* __restrict__ dskip)
{
    constexpr int BUFE = 384 * 64;
    __shared__ u16 lds[2 * BUFE];
    const int tid = threadIdx.x, lane = tid & 63, wid = tid >> 6;
    const int wm = wid >> 2, wn = wid & 3;
    const int l15 = lane & 15, lg = lane >> 4, l7 = lane & 7;
    const int bid = blockIdx.x;
    const int swz = (bid & 7) * (NBX * 4) + (bid >> 3);
    const int by = swz / NBX, bx = swz % NBX;
    const int m0 = by * 256, n0 = bx * 128;

    const int rl = lane >> 3;
    const int scol = ((lane & 7) ^ rl) * 8;
    const u16* pS[3][2];
    #pragma unroll
    for (int j = 0; j < 2; ++j) {
        const int rloc = (wid * 2 + j) * 8 + rl;
        pS[0][j] = A  + (size_t)(m0 + rloc)       * K + scol;
        pS[1][j] = A  + (size_t)(m0 + 128 + rloc) * K + scol;
        pS[2][j] = Bm + (size_t)(n0 + rloc)       * K + scol;
    }

    f32x4 accA[8][2] = {};

    #pragma unroll
    for (int t = 0; t < 2; ++t) { STAGE(0, t); STAGE(1, t); STAGE(2, t); }
    VMK(0);
    __builtin_amdgcn_s_barrier();

    const int NI = NT >> 1;
    for (int i = 0; i < NI; ++i) {
        const bool s1 = (i > 0);
        const bool s2 = (2 * i + 2 < NT);
        const bool s3 = (2 * i + 3 < NT);
        v8bf af[4][2], bf[2][2];
        // P0: buf0, mf0-3 (+B)
        p4_read<0, true>(lds, wm, wn, l15, lg, l7, af, bf);
        if (s1) { STAGE(0, 1); STAGE(1, 1); }
        BAR_MMA_BEGIN; p4_mma<0>(af, bf, accA); MMA_END; ENDBAR;
        // P1: buf0, mf4-7
        p4_read<4, false>(lds, wm, wn, l15, lg, l7, af, bf);
        if (s2) STAGE(2, 0);
        BAR_MMA_BEGIN; p4_mma<4>(af, bf, accA); MMA_END;
        if (s2) { VMK(2); } else { VMK(0); }
        ENDBAR;
        // P2: buf1, mf0-3 (+B)
        p4_read<0, true>(lds + BUFE, wm, wn, l15, lg, l7, af, bf);
        if (s2) { STAGE(0, 0); STAGE(1, 0); }
        BAR_MMA_BEGIN; p4_mma<0>(af, bf, accA); MMA_END; ENDBAR;
        // P3: buf1, mf4-7
        p4_read<4, false>(lds + BUFE, wm, wn, l15, lg, l7, af, bf);
        if (s3) STAGE(2, 1);
        BAR_MMA_BEGIN; p4_mma<4>(af, bf, accA); MMA_END;
        if (s3) { VMK(2); } else { VMK(0); }
        ENDBAR;
    }

    #pragma unroll
    for (int mf = 0; mf < 8; ++mf)
    #pragma unroll
    for (int cf = 0; cf < 2; ++cf)
    #pragma unroll
    for (int q = 0; q < 4; ++q) {
        const int r = m0 + wm * 128 + mf * 16 + lg * 4 + q;
        const int c = n0 + wn * 32 + cf * 16 + l15;
        const size_t o = (size_t)r * NO + c;
        const float v = accA[mf][cf][q];
        if constexpr (EPI == 1) {
            const float u = us2f(aux[o]);
            const float t2 = v + dskip[c] * u;
            ((u16*)Cout)[o] = f2us(gelu_f(t2) + u);
        } else {
            ((float*)Cout)[o] = v + us2f(aux[o]);
        }
    }
}

// ---------- workspace layout (bytes) ----------
static constexpr size_t OFF_FX  = 0;                              // bf16 16.78MB
static constexpr size_t OFF_BU  = 16777216;                       // f32   4.19MB
static constexpr size_t OFF_A2  = 20971520;                       // bf16  2.10MB
static constexpr size_t OFF_E2  = 0;                              // bf16 33.55MB (alias)
static constexpr size_t OFF_FX2 = 33554432;                       // bf16 16.78MB
static constexpr size_t OFF_BB  = 50331648;                       // bf16  0.26MB
static constexpr size_t OFF_C2  = 50593792;                       // bf16  0.26MB
static constexpr size_t OFF_WE  = 50855936;                       // bf16  8.39MB
static constexpr size_t OFF_WD  = 59244544;                       // bf16  4.19MB

extern "C" void kernel_launch(void* const* d_in, const int* in_sizes, int n_in,
                              void* d_out, int out_size, void* d_ws, size_t ws_size,
                              hipStream_t stream) {
    const float* x    = (const float*)d_in[0];
    const float* l1g  = (const float*)d_in[1];
    const float* l1b  = (const float*)d_in[2];
    const float* l2g  = (const float*)d_in[3];
    const float* l2b  = (const float*)d_in[4];
    const float* Lre  = (const float*)d_in[5];
    const float* Lim  = (const float*)d_in[6];
    const float* Bre  = (const float*)d_in[7];
    const float* Bim  = (const float*)d_in[8];
    const float* Cre  = (const float*)d_in[9];
    const float* Cim  = (const float*)d_in[10];
    const float* Dsk  = (const float*)d_in[11];
    const float* lst  = (const float*)d_in[12];
    const float* Wenc = (const float*)d_in[13];
    const float* Wdec = (const float*)d_in[14];
    float* out = (float*)d_out;

    char* ws = (char*)d_ws;
    u16*   fx   = (u16*)(ws + OFF_FX);
    float* Bu   = (float*)(ws + OFF_BU);
    u16*   A2   = (u16*)(ws + OFF_A2);
    u16*   e2   = (u16*)(ws + OFF_E2);
    u16*   fx2  = (u16*)(ws + OFF_FX2);
    u16*   Bbar = (u16*)(ws + OFF_BB);
    u16*   C2   = (u16*)(ws + OFF_C2);
    u16*   WeB  = (u16*)(ws + OFF_WE);
    u16*   WdB  = (u16*)(ws + OFF_WD);
    u16*   h    = (u16*)d_out;           // h (bf16) in d_out's first half

    // 1) fx = LN1(x)
    ln_kernel<float><<<8192, 256, 0, stream>>>(x, l1g, l1b, fx);
    // 1b) weight conversions + B_bar / C2 precompute (fused)
    prepall_kernel<<<3584, 256, 0, stream>>>(Wenc, WeB, Wdec, WdB,
                                             Lre, Lim, lst, Bre, Bim, Cre, Cim,
                                             Bbar, C2);
    // 2) Bu = fx @ Bbar^T
    gemm_small_kernel<64, 64><<<dim3(2, 128), 64, 0, stream>>>(
        fx, Bbar, Bu, 128, 1024);
    // 3) scan -> A2
    scan_kernel<<<256, 256, 0, stream>>>(Bu, Lre, Lim, lst, A2);
    // 4) h = gelu(A2 @ C2^T + Dskip*fx) + fx
    gemm4p_kernel<1, 8><<<256, 512, 0, stream>>>(
        A2, C2, h, 128, 1024, 2, fx, Dsk);
    // 5) fx2 = LN2(h)
    ln_kernel<u16><<<8192, 256, 0, stream>>>(h, l2g, l2b, fx2);
    // 6) e2 = (fx2 @ We[:2048]^T) * gelu(fx2 @ We[2048:]^T)
    geglu8p_kernel<16><<<512, 512, 0, stream>>>(fx2, WeB, e2, 1024, 2048, 16);
    // 7) out = e2 @ WdB^T + fx2
    gemm4p_kernel<3, 8><<<256, 512, 0, stream>>>(
        e2, WdB, out, 2048, 1024, 32, fx2, nullptr);

    (void)in_sizes; (void)n_in; (void)out_size; (void)ws_size;
}